// Round 1
// 521.370 us; speedup vs baseline: 1.0059x; 1.0059x over previous
//
#include <hip/hip_runtime.h>
#include <hip/hip_bf16.h>
#include <math.h>

#define S_ 2048
#define D_ 1024
#define H_ 4
#define HD_ 256
#define B_ 4

typedef __hip_bfloat16 bf16;
typedef short s16x8 __attribute__((ext_vector_type(8)));
typedef float f32x4 __attribute__((ext_vector_type(4)));

// async global->LDS, 16B per lane; LDS dest is wave-uniform base + lane*16
#define GLOAD16(g, l)                                             \
    __builtin_amdgcn_global_load_lds(                             \
        (const __attribute__((address_space(1))) void*)(g),       \
        (__attribute__((address_space(3))) void*)(l), 16, 0, 0)

// ---------------------------------------------------------------------------
// MFMA NT GEMM: C[m,n] = sum_k A[m,k]*B[n,k], A/B bf16 row-major.
// 128x128 tile, BK=32, 256 threads = 4 waves (2x2), each wave 4x4 frags of
// 16x16x32 bf16 MFMA. M,N multiples of 128; K multiple of 32.
// z decomposed: zb = z/zdiv, zh = z%zdiv; per-operand (b,h) strides in elems.
// MODE: 0 = fp32 store, 1 = bf16 store, 3 = fp32 store + legal-bias (h=zh,
//       bias batch = bbase + zb).
// ---------------------------------------------------------------------------
template <int MODE>
__global__ __launch_bounds__(256) void mfma_nt(
    int K,
    const bf16* __restrict__ A, int lda, long sA_b, long sA_h,
    const bf16* __restrict__ Bm, int ldb, long sB_b, long sB_h,
    void* __restrict__ Cp, int ldc, long sC_b, long sC_h,
    int zdiv, int bbase,
    const double* __restrict__ mag1d, const double* __restrict__ v3d,
    const double* __restrict__ meand, const float* __restrict__ bias_sc)
{
    __shared__ __align__(16) short As[128 * 32];
    __shared__ __align__(16) short Bs[128 * 32];

    const int tid = threadIdx.x;
    const int w = tid >> 6, lane = tid & 63;
    const int srow = lane >> 2, scol = (lane & 3) << 3;  // staging: 16 rows/inst
    const int quad = lane >> 4, r = lane & 15;           // mfma fragment coords
    const int wr = (w >> 1) * 64, wc = (w & 1) * 64;     // wave's 64x64 quadrant
    const int zb = blockIdx.z / zdiv, zh = blockIdx.z % zdiv;

    const bf16* Ap = A + (size_t)zb * sA_b + (size_t)zh * sA_h +
                     (size_t)blockIdx.y * 128 * lda;
    const bf16* Bp = Bm + (size_t)zb * sB_b + (size_t)zh * sB_h +
                     (size_t)blockIdx.x * 128 * ldb;

    f32x4 acc[4][4] = {};

    for (int k0 = 0; k0 < K; k0 += 32) {
        if (k0) __syncthreads();  // previous compute done before LDS overwrite
#pragma unroll
        for (int l = 0; l < 2; l++) {
            GLOAD16(Ap + (size_t)(w * 32 + l * 16 + srow) * lda + (k0 + scol),
                    &As[(w * 32 + l * 16) * 32]);
            GLOAD16(Bp + (size_t)(w * 32 + l * 16 + srow) * ldb + (k0 + scol),
                    &Bs[(w * 32 + l * 16) * 32]);
        }
        __syncthreads();  // drains vmcnt (compiler emits waitcnt before barrier)

        s16x8 af[4], bfv[4];
        const s16x8* A8 = (const s16x8*)As;
        const s16x8* B8 = (const s16x8*)Bs;
#pragma unroll
        for (int i = 0; i < 4; i++) af[i] = A8[(wr + i * 16 + r) * 4 + quad];
#pragma unroll
        for (int j = 0; j < 4; j++) bfv[j] = B8[(wc + j * 16 + r) * 4 + quad];
#pragma unroll
        for (int i = 0; i < 4; i++)
#pragma unroll
            for (int j = 0; j < 4; j++)
                acc[i][j] = __builtin_amdgcn_mfma_f32_16x16x32_bf16(
                    af[i], bfv[j], acc[i][j], 0, 0, 0);
    }

    // C/D layout: col = lane&15, row = quad*4 + reg   [m89-verified]
    const int row0 = blockIdx.y * 128 + wr + quad * 4;
    const int col0 = blockIdx.x * 128 + wc + r;

    if (MODE == 0) {
        float* C = (float*)Cp + (size_t)zb * sC_b + (size_t)zh * sC_h;
#pragma unroll
        for (int i = 0; i < 4; i++)
#pragma unroll
            for (int j = 0; j < 4; j++)
#pragma unroll
                for (int p = 0; p < 4; p++)
                    C[(size_t)(row0 + i * 16 + p) * ldc + (col0 + j * 16)] = acc[i][j][p];
    } else if (MODE == 1) {
        bf16* C = (bf16*)Cp + (size_t)zb * sC_b + (size_t)zh * sC_h;
#pragma unroll
        for (int i = 0; i < 4; i++)
#pragma unroll
            for (int j = 0; j < 4; j++)
#pragma unroll
                for (int p = 0; p < 4; p++)
                    C[(size_t)(row0 + i * 16 + p) * ldc + (col0 + j * 16)] =
                        __float2bfloat16(acc[i][j][p]);
    } else {  // MODE 3: scores + legal bias; h = zh, batch = bbase + zb
        float* C = (float*)Cp + (size_t)zb * sC_b + (size_t)zh * sC_h;
        const int h = zh;
        const int bbatch = bbase + zb;
        const float bsc = bias_sc[h];
        if (h == 0) {  // causal triu(k=1)
#pragma unroll
            for (int i = 0; i < 4; i++)
#pragma unroll
                for (int j = 0; j < 4; j++)
#pragma unroll
                    for (int p = 0; p < 4; p++) {
                        const int rr = row0 + i * 16 + p, c = col0 + j * 16;
                        C[(size_t)rr * ldc + c] = acc[i][j][p] + ((c > rr) ? bsc : 0.0f);
                    }
        } else if (h == 2) {  // proximity
#pragma unroll
            for (int i = 0; i < 4; i++)
#pragma unroll
                for (int j = 0; j < 4; j++)
#pragma unroll
                    for (int p = 0; p < 4; p++) {
                        const int rr = row0 + i * 16 + p, c = col0 + j * 16;
                        int d = c - rr; d = d < 0 ? -d : d;
                        C[(size_t)rr * ldc + c] =
                            acc[i][j][p] + bsc * expf(-(float)d * (1.0f / 2048.0f));
                    }
        } else {  // h==1 intent (> mean) / h==3 violation (> 0.5), exact fp64 compare
            const double* src = (h == 1) ? mag1d : v3d;
            const double thr = (h == 1) ? meand[0] : 0.5;
            double rv[16], cv[4];
#pragma unroll
            for (int i = 0; i < 4; i++)
#pragma unroll
                for (int p = 0; p < 4; p++)
                    rv[i * 4 + p] = src[(size_t)bbatch * S_ + row0 + i * 16 + p];
#pragma unroll
            for (int j = 0; j < 4; j++)
                cv[j] = src[(size_t)bbatch * S_ + col0 + j * 16];
#pragma unroll
            for (int i = 0; i < 4; i++)
#pragma unroll
                for (int j = 0; j < 4; j++)
#pragma unroll
                    for (int p = 0; p < 4; p++) {
                        const int rr = row0 + i * 16 + p, c = col0 + j * 16;
                        C[(size_t)rr * ldc + c] =
                            acc[i][j][p] + ((rv[i * 4 + p] * cv[j] > thr) ? bsc : 0.0f);
                    }
        }
    }
}

// ---------------------------------------------------------------------------
// Dedicated batched P.V GEMM: C[b, s, h*HD + e] = sum_t P[b,h,s,t] * V[t,e].
// Tile 128x256 (full hd in N -> P read exactly once), 512 threads = 8 waves
// (2M x 4N), wave tile 64x64 = 4x4 frags. Double-buffered LDS with prefetch:
// stage(t+1) issued before compute(t); ONE barrier per K-step (the compiler's
// vmcnt(0)+lgkmcnt(0) drain at __syncthreads covers both buffers' hazards).
// Grid = 256 blocks (16 row-blocks x 16 (b,h)); XCD-clustered mapping keeps
// each (b,h)'s shared V panel (1 MB) hot in one XCD's L2.
// ---------------------------------------------------------------------------
__global__ __launch_bounds__(512) void mfma_pv(const bf16* __restrict__ Pm,
                                               const bf16* __restrict__ Vt,
                                               bf16* __restrict__ Cc) {
    // per buffer: A 128x32 (4096 shorts) | B 256x32 (8192 shorts) = 24 KB
    __shared__ __align__(16) short L[2][12288];

    const int tid = threadIdx.x;
    const int w = tid >> 6, lane = tid & 63;
    const int quad = lane >> 4, r = lane & 15;
    const int wr = (w >> 2) * 64, wc = (w & 3) * 64;  // wave's 64x64 subtile

    // XCD-clustered decomposition of 256 blocks: xcd = bid%8 (HW round-robin),
    // each XCD owns 2 (b,h) pairs x 16 row-blocks.
    const int bid = blockIdx.x;
    const int bh = (bid & 7) * 2 + ((bid >> 3) >> 4);  // 0..15, bijective
    const int rb = (bid >> 3) & 15;                    // row-block 0..15
    const int b = bh >> 2, h = bh & 3;

    const bf16* Ap = Pm + ((size_t)bh * S_ + (size_t)rb * 128) * S_;  // P[b,h] rows
    const bf16* Bp = Vt + (size_t)(h * B_ + b) * HD_ * S_;            // V^T panel

    const int srow = tid >> 2, scol = (tid & 3) << 3;  // 4 threads per 32-k row
    const int wbase = w * 512;                          // wave's 16-row LDS slab

    f32x4 acc[4][4] = {};

    auto stage = [&](int bs, int k0) {
        short* sb = &L[bs][0];
        GLOAD16(Ap + (size_t)srow * S_ + (k0 + scol), sb + wbase);               // P rows 0..127
        GLOAD16(Bp + (size_t)srow * S_ + (k0 + scol), sb + 4096 + wbase);        // V rows 0..127
        GLOAD16(Bp + (size_t)(128 + srow) * S_ + (k0 + scol), sb + 8192 + wbase);// V rows 128..255
    };
    auto compute = [&](int bs) {
        const s16x8* A8 = (const s16x8*)&L[bs][0];
        const s16x8* B8 = (const s16x8*)&L[bs][4096];
        s16x8 af[4], bfv[4];
#pragma unroll
        for (int i = 0; i < 4; i++) af[i] = A8[(wr + i * 16 + r) * 4 + quad];
#pragma unroll
        for (int j = 0; j < 4; j++) bfv[j] = B8[(wc + j * 16 + r) * 4 + quad];
#pragma unroll
        for (int i = 0; i < 4; i++)
#pragma unroll
            for (int j = 0; j < 4; j++)
                acc[i][j] = __builtin_amdgcn_mfma_f32_16x16x32_bf16(
                    af[i], bfv[j], acc[i][j], 0, 0, 0);
    };

    stage(0, 0);
    __syncthreads();
    int cur = 0;
#pragma unroll 1
    for (int t = 0; t < 63; ++t) {
        stage(cur ^ 1, (t + 1) * 32);  // prefetch next tile; latency hides under MFMA
        compute(cur);
        __syncthreads();               // drains vmcnt (next buf ready) + lgkm (this buf free)
        cur ^= 1;
    }
    compute(cur);  // last tile (no prefetch)

    const int row0 = rb * 128 + wr + quad * 4;
    const int col0 = h * HD_ + wc + r;
    bf16* C = Cc + (size_t)b * S_ * D_;
#pragma unroll
    for (int i = 0; i < 4; i++)
#pragma unroll
        for (int j = 0; j < 4; j++)
#pragma unroll
            for (int p = 0; p < 4; p++)
                C[(size_t)(row0 + i * 16 + p) * D_ + col0 + j * 16] =
                    __float2bfloat16(acc[i][j][p]);
}

// fp32 -> bf16 (optionally scaled), 4 elems/thread
__global__ __launch_bounds__(256) void cvt_bf16(const float* __restrict__ in,
                                                bf16* __restrict__ out, int n,
                                                float scale) {
    const size_t i0 = ((size_t)blockIdx.x * 256 + threadIdx.x) * 4;
    if (i0 + 3 < (size_t)n) {
        const float4 v = *(const float4*)(in + i0);
        out[i0 + 0] = __float2bfloat16(v.x * scale);
        out[i0 + 1] = __float2bfloat16(v.y * scale);
        out[i0 + 2] = __float2bfloat16(v.z * scale);
        out[i0 + 3] = __float2bfloat16(v.w * scale);
    }
}

// Vraw [H, B*S, hd] -> Vt [H, B, hd, S]  (64x64 bf16 LDS tile transpose)
__global__ __launch_bounds__(256) void transpose_v(const bf16* __restrict__ in,
                                                   bf16* __restrict__ out) {
    const int h = blockIdx.z / B_, b = blockIdx.z % B_;
    const int e0 = blockIdx.x * 64, s0 = blockIdx.y * 64;
    __shared__ short t[64][66];
    const int tid = threadIdx.x;
    const int rr = tid >> 2;            // 0..63
    const int cc = (tid & 3) << 4;      // 0,16,32,48
    const bf16* ip = in + (((size_t)h * B_ * S_) + (size_t)b * S_ + s0) * HD_ + e0;
    const s16x8 v0 = *(const s16x8*)(ip + (size_t)rr * HD_ + cc);
    const s16x8 v1 = *(const s16x8*)(ip + (size_t)rr * HD_ + cc + 8);
#pragma unroll
    for (int i = 0; i < 8; i++) {
        t[rr][cc + i] = v0[i];
        t[rr][cc + 8 + i] = v1[i];
    }
    __syncthreads();
    bf16* op = out + (((size_t)h * B_ + b) * HD_ + e0 + rr) * S_ + s0 + cc;
    s16x8 o0, o1;
#pragma unroll
    for (int i = 0; i < 8; i++) {
        o0[i] = t[cc + i][rr];
        o1[i] = t[cc + 8 + i][rr];
    }
    *(s16x8*)op = o0;
    *(s16x8*)(op + 8) = o1;
}

// mag1[b,s] = ||emb[b,s,256:512]|| (fp64), v3[b,s] = emb[b,s,1023]
__global__ __launch_bounds__(256) void prep_kernel(const float* __restrict__ emb,
                                                   double* __restrict__ mag1d,
                                                   double* __restrict__ v3d) {
    const long row = blockIdx.x;
    const int tid = threadIdx.x;
    const float x = emb[row * D_ + 256 + tid];
    __shared__ double red[256];
    red[tid] = (double)x * (double)x;
    __syncthreads();
    for (int off = 128; off > 0; off >>= 1) {
        if (tid < off) red[tid] += red[tid + off];
        __syncthreads();
    }
    if (tid == 0) {
        mag1d[row] = sqrt(red[0]);
        v3d[row] = (double)emb[row * D_ + 1023];
    }
}

__global__ __launch_bounds__(256) void mean_kernel(const double* __restrict__ mag1d,
                                                   double* __restrict__ meand) {
    const int tid = threadIdx.x;
    __shared__ double red[256];
    double acc = 0.0;
    for (int b = 0; b < B_; b++) {
        double ss = 0.0;
        for (int i = tid; i < S_; i += 256) ss += mag1d[(long)b * S_ + i];
        __syncthreads();
        red[tid] = ss;
        __syncthreads();
        for (int off = 128; off > 0; off >>= 1) {
            if (tid < off) red[tid] += red[tid + off];
            __syncthreads();
        }
        if (tid == 0) {
            const double rb = red[0] / (double)S_;
            acc += rb * rb;
        }
        __syncthreads();
    }
    if (tid == 0) meand[0] = acc / (double)B_;
}

// Per row s (one b): softmax over all 4 heads (fp32, same op order as R2),
// write P bf16 (layout via p_h/p_row strides), accumulate avgw + rowsum.
__global__ __launch_bounds__(256) void softmax_fused(
    const float* __restrict__ scores, bf16* __restrict__ P, long p_h, int p_row,
    float* __restrict__ avgw, float* __restrict__ rowsum) {
    const int s = blockIdx.x, tid = threadIdx.x;
    __shared__ float red[256];
    float wacc[8] = {0, 0, 0, 0, 0, 0, 0, 0};
    for (int h = 0; h < H_; h++) {
        const float* rp = scores + ((size_t)h * S_ + s) * S_;
        bf16* pp = P + (size_t)h * p_h + (size_t)s * p_row;
        float v[8];
        float m = -1e30f;
#pragma unroll
        for (int i = 0; i < 8; i++) {
            v[i] = rp[tid + 256 * i];
            m = fmaxf(m, v[i]);
        }
        red[tid] = m;
        __syncthreads();
        for (int off = 128; off > 0; off >>= 1) {
            if (tid < off) red[tid] = fmaxf(red[tid], red[tid + off]);
            __syncthreads();
        }
        m = red[0];
        __syncthreads();
        float sum = 0.0f;
#pragma unroll
        for (int i = 0; i < 8; i++) {
            v[i] = expf(v[i] - m);
            sum += v[i];
        }
        red[tid] = sum;
        __syncthreads();
        for (int off = 128; off > 0; off >>= 1) {
            if (tid < off) red[tid] += red[tid + off];
            __syncthreads();
        }
        const float inv = 1.0f / red[0];
        __syncthreads();
#pragma unroll
        for (int i = 0; i < 8; i++) {
            const float wv = v[i] * inv;
            pp[tid + 256 * i] = __float2bfloat16(wv);
            wacc[i] += wv;
        }
    }
    float asum = 0.0f;
#pragma unroll
    for (int i = 0; i < 8; i++) {
        const float a = wacc[i] * 0.25f;
        avgw[(size_t)s * S_ + tid + 256 * i] = a;
        asum += a;
    }
    red[tid] = asum;
    __syncthreads();
    for (int off = 128; off > 0; off >>= 1) {
        if (tid < off) red[tid] += red[tid + off];
        __syncthreads();
    }
    if (tid == 0) rowsum[s] = red[0];
}

// y = proj + Wo_b + emb; LayerNorm(y) in place
__global__ __launch_bounds__(256) void ln_kernel(float* __restrict__ out,
                                                 const float* __restrict__ emb,
                                                 const float* __restrict__ wob,
                                                 const float* __restrict__ g,
                                                 const float* __restrict__ beta) {
    const long row = blockIdx.x;
    float* o = out + row * D_;
    const float* e = emb + row * D_;
    const int tid = threadIdx.x;
    __shared__ float red[256];
    float v[4];
    float sum = 0.0f;
#pragma unroll
    for (int i = 0; i < 4; i++) {
        const int c = tid + 256 * i;
        v[i] = o[c] + wob[c] + e[c];
        sum += v[i];
    }
    red[tid] = sum;
    __syncthreads();
    for (int off = 128; off > 0; off >>= 1) {
        if (tid < off) red[tid] += red[tid + off];
        __syncthreads();
    }
    const float mu = red[0] * (1.0f / 1024.0f);
    __syncthreads();
    float vs = 0.0f;
#pragma unroll
    for (int i = 0; i < 4; i++) {
        const float d = v[i] - mu;
        vs += d * d;
    }
    red[tid] = vs;
    __syncthreads();
    for (int off = 128; off > 0; off >>= 1) {
        if (tid < off) red[tid] += red[tid + off];
        __syncthreads();
    }
    const float var = red[0] * (1.0f / 1024.0f);
    const float inv = 1.0f / sqrtf(var + 1e-5f);
#pragma unroll
    for (int i = 0; i < 4; i++) {
        const int c = tid + 256 * i;
        o[c] = (v[i] - mu) * inv * g[c] + beta[c];
    }
}

__global__ __launch_bounds__(256) void guilt_kernel(const float* __restrict__ rowsum,
                                                    float* __restrict__ guilt) {
    const int b = blockIdx.x, tid = threadIdx.x;
    const float* r = rowsum + (long)b * S_;
    float* gq = guilt + (long)b * S_;
    __shared__ float red[256];
    float v[8];
    float m = -1e30f;
#pragma unroll
    for (int i = 0; i < 8; i++) {
        v[i] = r[tid + 256 * i];
        m = fmaxf(m, v[i]);
    }
    red[tid] = m;
    __syncthreads();
    for (int off = 128; off > 0; off >>= 1) {
        if (tid < off) red[tid] = fmaxf(red[tid], red[tid + off]);
        __syncthreads();
    }
    m = red[0];
    __syncthreads();
    float sum = 0.0f;
#pragma unroll
    for (int i = 0; i < 8; i++) {
        v[i] = expf(v[i] - m);
        sum += v[i];
    }
    red[tid] = sum;
    __syncthreads();
    for (int off = 128; off > 0; off >>= 1) {
        if (tid < off) red[tid] += red[tid + off];
        __syncthreads();
    }
    const float inv = 1.0f / red[0];
#pragma unroll
    for (int i = 0; i < 8; i++) gq[tid + 256 * i] = v[i] * inv;
}

extern "C" void kernel_launch(void* const* d_in, const int* in_sizes, int n_in,
                              void* d_out, int out_size, void* d_ws, size_t ws_size,
                              hipStream_t stream) {
    const float* emb = (const float*)d_in[0];
    const float* Wq = (const float*)d_in[1];
    const float* Wk = (const float*)d_in[2];
    const float* Wv = (const float*)d_in[3];
    const float* bias_sc = (const float*)d_in[4];
    const float* Wo_w = (const float*)d_in[5];
    const float* Wo_b = (const float*)d_in[6];
    const float* ln_g = (const float*)d_in[7];
    const float* ln_bt = (const float*)d_in[8];

    char* ws = (char*)d_ws;
    size_t off = 0;
    auto alloc = [&](size_t bytes) {
        size_t o = off;
        off = (off + bytes + 255) & ~(size_t)255;
        return o;
    };
    bf16* embb = (bf16*)(ws + alloc((size_t)B_ * S_ * D_ * 2));
    bf16* concat = embb;  // alias: embb dead after QKV GEMMs, concat written later
    bf16* Qm = (bf16*)(ws + alloc((size_t)H_ * B_ * S_ * HD_ * 2));  // [H,B*S,hd]
    bf16* Km = (bf16*)(ws + alloc((size_t)H_ * B_ * S_ * HD_ * 2));
    bf16* Vtb = (bf16*)(ws + alloc((size_t)H_ * B_ * HD_ * S_ * 2)); // [H,B,hd,S]
    bf16* Wqb = (bf16*)(ws + alloc((size_t)H_ * HD_ * HD_ * 2));
    bf16* Wkb = (bf16*)(ws + alloc((size_t)H_ * HD_ * HD_ * 2));
    bf16* Wvb = (bf16*)(ws + alloc((size_t)H_ * HD_ * HD_ * 2));
    bf16* Wob = (bf16*)(ws + alloc((size_t)D_ * D_ * 2));
    double* mag1d = (double*)(ws + alloc((size_t)B_ * S_ * 8));
    double* v3d = (double*)(ws + alloc((size_t)B_ * S_ * 8));
    double* meand = (double*)(ws + alloc(256));
    float* rowsum = (float*)(ws + alloc((size_t)B_ * S_ * 4));
    float* scores = (float*)(ws + alloc((size_t)H_ * S_ * S_ * 4));  // one b
    bf16* Vraw = (bf16*)scores;  // alias: Vraw consumed (transposed) before scores b=0
    bf16* P = (bf16*)(ws + off);  // Path A only: [B,H,S,S] bf16
    const size_t need_batched = off + (size_t)B_ * H_ * S_ * S_ * 2;
    const bool batched = ws_size >= need_batched;

    float* outp = (float*)d_out;
    float* avgw = outp + (size_t)B_ * S_ * D_;
    float* guilt = avgw + (size_t)B_ * S_ * S_;

    // casts (Q-scale 1/16 folded into Wq)
    cvt_bf16<<<(B_ * S_ * D_) / 1024, 256, 0, stream>>>(emb, embb, B_ * S_ * D_, 1.0f);
    cvt_bf16<<<(H_ * HD_ * HD_) / 1024, 256, 0, stream>>>(Wq, Wqb, H_ * HD_ * HD_, 0.0625f);
    cvt_bf16<<<(H_ * HD_ * HD_) / 1024, 256, 0, stream>>>(Wk, Wkb, H_ * HD_ * HD_, 1.0f);
    cvt_bf16<<<(H_ * HD_ * HD_) / 1024, 256, 0, stream>>>(Wv, Wvb, H_ * HD_ * HD_, 1.0f);
    cvt_bf16<<<(D_ * D_) / 1024, 256, 0, stream>>>(Wo_w, Wob, D_ * D_, 1.0f);

    prep_kernel<<<B_ * S_, 256, 0, stream>>>(emb, mag1d, v3d);
    mean_kernel<<<1, 256, 0, stream>>>(mag1d, meand);

    // QKV projections: MFMA, M = B*S (=8192), N = hd, K = hd, z = head
    {
        const dim3 g(HD_ / 128, (B_ * S_) / 128, H_);
        const long sQ = (long)B_ * S_ * HD_;
        mfma_nt<1><<<g, 256, 0, stream>>>(HD_, embb, D_, 0, HD_,
                                          Wqb, HD_, 0, (long)HD_ * HD_,
                                          Qm, HD_, 0, sQ, H_, 0,
                                          nullptr, nullptr, nullptr, nullptr);
        mfma_nt<1><<<g, 256, 0, stream>>>(HD_, embb, D_, 0, HD_,
                                          Wkb, HD_, 0, (long)HD_ * HD_,
                                          Km, HD_, 0, sQ, H_, 0,
                                          nullptr, nullptr, nullptr, nullptr);
        mfma_nt<1><<<g, 256, 0, stream>>>(HD_, embb, D_, 0, HD_,
                                          Wvb, HD_, 0, (long)HD_ * HD_,
                                          Vraw, HD_, 0, sQ, H_, 0,
                                          nullptr, nullptr, nullptr, nullptr);
    }
    transpose_v<<<dim3(HD_ / 64, S_ / 64, H_ * B_), 256, 0, stream>>>(Vraw, Vtb);

    for (int b = 0; b < B_; b++) {
        // scores[h,s,t] = Q.K^T + bias  (fp32 out, per-b buffer stays L3-warm)
        mfma_nt<3><<<dim3(S_ / 128, S_ / 128, H_), 256, 0, stream>>>(
            HD_,
            Qm + (size_t)b * S_ * HD_, HD_, 0, (long)B_ * S_ * HD_,
            Km + (size_t)b * S_ * HD_, HD_, 0, (long)B_ * S_ * HD_,
            scores, S_, 0, (long)S_ * S_,
            H_, b, mag1d, v3d, meand, bias_sc);
        if (batched) {
            softmax_fused<<<S_, 256, 0, stream>>>(
                scores, P + (size_t)b * H_ * S_ * S_, (long)S_ * S_, S_,
                avgw + (size_t)b * S_ * S_, rowsum + (size_t)b * S_);
        } else {
            // P bf16 in place over the fp32 scores rows (row stride 2S)
            softmax_fused<<<S_, 256, 0, stream>>>(
                scores, (bf16*)scores, 2L * S_ * S_, 2 * S_,
                avgw + (size_t)b * S_ * S_, rowsum + (size_t)b * S_);
            mfma_nt<1><<<dim3(HD_ / 128, S_ / 128, H_), 256, 0, stream>>>(
                S_,
                (const bf16*)scores, 2 * S_, 0, 2L * S_ * S_,
                Vtb + (size_t)b * HD_ * S_, S_, 0, (long)B_ * HD_ * S_,
                concat + (size_t)b * S_ * D_, D_, 0, HD_,
                H_, 0, nullptr, nullptr, nullptr, nullptr);
        }
    }
    if (batched) {
        // attended = P.V for all (b,h): dedicated 128x256-tile double-buffered
        // kernel, P read exactly once, XCD-clustered V reuse.
        mfma_pv<<<256, 512, 0, stream>>>(P, Vtb, concat);
    }

    // out = concat @ Wo^T (MFMA, bf16 Wo)
    mfma_nt<0><<<dim3(D_ / 128, (B_ * S_) / 128, 1), 256, 0, stream>>>(
        D_, concat, D_, 0, 0, Wob, D_, 0, 0, outp, D_, 0, 0,
        1, 0, nullptr, nullptr, nullptr, nullptr);

    ln_kernel<<<B_ * S_, 256, 0, stream>>>(outp, emb, Wo_b, ln_g, ln_bt);
    guilt_kernel<<<B_, 256, 0, stream>>>(rowsum, guilt);
}

// Round 2
// 507.057 us; speedup vs baseline: 1.0343x; 1.0282x over previous
//
#include <hip/hip_runtime.h>
#include <hip/hip_bf16.h>
#include <math.h>

#define S_ 2048
#define D_ 1024
#define H_ 4
#define HD_ 256
#define B_ 4

typedef __hip_bfloat16 bf16;
typedef short s16x8 __attribute__((ext_vector_type(8)));
typedef float f32x4 __attribute__((ext_vector_type(4)));

// async global->LDS, 16B per lane; LDS dest is wave-uniform base + lane*16
#define GLOAD16(g, l)                                             \
    __builtin_amdgcn_global_load_lds(                             \
        (const __attribute__((address_space(1))) void*)(g),       \
        (__attribute__((address_space(3))) void*)(l), 16, 0, 0)

// ---------------------------------------------------------------------------
// MFMA NT GEMM: C[m,n] = sum_k A[m,k]*B[n,k], A/B bf16 row-major.
// 128x128 tile, BK=32, 256 threads = 4 waves (2x2), each wave 4x4 frags of
// 16x16x32 bf16 MFMA. M,N multiples of 128; K multiple of 32.
// z decomposed: zb = z/zdiv, zh = z%zdiv; per-operand (b,h) strides in elems.
// MODE: 0 = fp32 store, 1 = bf16 store, 3 = fp32 store + legal-bias (h=zh,
//       bias batch = bbase + zb).
// ---------------------------------------------------------------------------
template <int MODE>
__global__ __launch_bounds__(256) void mfma_nt(
    int K,
    const bf16* __restrict__ A, int lda, long sA_b, long sA_h,
    const bf16* __restrict__ Bm, int ldb, long sB_b, long sB_h,
    void* __restrict__ Cp, int ldc, long sC_b, long sC_h,
    int zdiv, int bbase,
    const double* __restrict__ mag1d, const double* __restrict__ v3d,
    const double* __restrict__ meand, const float* __restrict__ bias_sc)
{
    __shared__ __align__(16) short As[128 * 32];
    __shared__ __align__(16) short Bs[128 * 32];

    const int tid = threadIdx.x;
    const int w = tid >> 6, lane = tid & 63;
    const int srow = lane >> 2, scol = (lane & 3) << 3;  // staging: 16 rows/inst
    const int quad = lane >> 4, r = lane & 15;           // mfma fragment coords
    const int wr = (w >> 1) * 64, wc = (w & 1) * 64;     // wave's 64x64 quadrant
    const int zb = blockIdx.z / zdiv, zh = blockIdx.z % zdiv;

    const bf16* Ap = A + (size_t)zb * sA_b + (size_t)zh * sA_h +
                     (size_t)blockIdx.y * 128 * lda;
    const bf16* Bp = Bm + (size_t)zb * sB_b + (size_t)zh * sB_h +
                     (size_t)blockIdx.x * 128 * ldb;

    f32x4 acc[4][4] = {};

    for (int k0 = 0; k0 < K; k0 += 32) {
        if (k0) __syncthreads();  // previous compute done before LDS overwrite
#pragma unroll
        for (int l = 0; l < 2; l++) {
            GLOAD16(Ap + (size_t)(w * 32 + l * 16 + srow) * lda + (k0 + scol),
                    &As[(w * 32 + l * 16) * 32]);
            GLOAD16(Bp + (size_t)(w * 32 + l * 16 + srow) * ldb + (k0 + scol),
                    &Bs[(w * 32 + l * 16) * 32]);
        }
        __syncthreads();  // drains vmcnt (compiler emits waitcnt before barrier)

        s16x8 af[4], bfv[4];
        const s16x8* A8 = (const s16x8*)As;
        const s16x8* B8 = (const s16x8*)Bs;
#pragma unroll
        for (int i = 0; i < 4; i++) af[i] = A8[(wr + i * 16 + r) * 4 + quad];
#pragma unroll
        for (int j = 0; j < 4; j++) bfv[j] = B8[(wc + j * 16 + r) * 4 + quad];
#pragma unroll
        for (int i = 0; i < 4; i++)
#pragma unroll
            for (int j = 0; j < 4; j++)
                acc[i][j] = __builtin_amdgcn_mfma_f32_16x16x32_bf16(
                    af[i], bfv[j], acc[i][j], 0, 0, 0);
    }

    // C/D layout: col = lane&15, row = quad*4 + reg   [m89-verified]
    const int row0 = blockIdx.y * 128 + wr + quad * 4;
    const int col0 = blockIdx.x * 128 + wc + r;

    if (MODE == 0) {
        float* C = (float*)Cp + (size_t)zb * sC_b + (size_t)zh * sC_h;
#pragma unroll
        for (int i = 0; i < 4; i++)
#pragma unroll
            for (int j = 0; j < 4; j++)
#pragma unroll
                for (int p = 0; p < 4; p++)
                    C[(size_t)(row0 + i * 16 + p) * ldc + (col0 + j * 16)] = acc[i][j][p];
    } else if (MODE == 1) {
        bf16* C = (bf16*)Cp + (size_t)zb * sC_b + (size_t)zh * sC_h;
#pragma unroll
        for (int i = 0; i < 4; i++)
#pragma unroll
            for (int j = 0; j < 4; j++)
#pragma unroll
                for (int p = 0; p < 4; p++)
                    C[(size_t)(row0 + i * 16 + p) * ldc + (col0 + j * 16)] =
                        __float2bfloat16(acc[i][j][p]);
    } else {  // MODE 3: scores + legal bias; h = zh, batch = bbase + zb
        float* C = (float*)Cp + (size_t)zb * sC_b + (size_t)zh * sC_h;
        const int h = zh;
        const int bbatch = bbase + zb;
        const float bsc = bias_sc[h];
        if (h == 0) {  // causal triu(k=1)
#pragma unroll
            for (int i = 0; i < 4; i++)
#pragma unroll
                for (int j = 0; j < 4; j++)
#pragma unroll
                    for (int p = 0; p < 4; p++) {
                        const int rr = row0 + i * 16 + p, c = col0 + j * 16;
                        C[(size_t)rr * ldc + c] = acc[i][j][p] + ((c > rr) ? bsc : 0.0f);
                    }
        } else if (h == 2) {  // proximity
#pragma unroll
            for (int i = 0; i < 4; i++)
#pragma unroll
                for (int j = 0; j < 4; j++)
#pragma unroll
                    for (int p = 0; p < 4; p++) {
                        const int rr = row0 + i * 16 + p, c = col0 + j * 16;
                        int d = c - rr; d = d < 0 ? -d : d;
                        C[(size_t)rr * ldc + c] =
                            acc[i][j][p] + bsc * expf(-(float)d * (1.0f / 2048.0f));
                    }
        } else {  // h==1 intent (> mean) / h==3 violation (> 0.5), exact fp64 compare
            const double* src = (h == 1) ? mag1d : v3d;
            const double thr = (h == 1) ? meand[0] : 0.5;
            double rv[16], cv[4];
#pragma unroll
            for (int i = 0; i < 4; i++)
#pragma unroll
                for (int p = 0; p < 4; p++)
                    rv[i * 4 + p] = src[(size_t)bbatch * S_ + row0 + i * 16 + p];
#pragma unroll
            for (int j = 0; j < 4; j++)
                cv[j] = src[(size_t)bbatch * S_ + col0 + j * 16];
#pragma unroll
            for (int i = 0; i < 4; i++)
#pragma unroll
                for (int j = 0; j < 4; j++)
#pragma unroll
                    for (int p = 0; p < 4; p++) {
                        const int rr = row0 + i * 16 + p, c = col0 + j * 16;
                        C[(size_t)rr * ldc + c] =
                            acc[i][j][p] + ((rv[i * 4 + p] * cv[j] > thr) ? bsc : 0.0f);
                    }
        }
    }
}

// ---------------------------------------------------------------------------
// Dedicated batched P.V GEMM: C[b, s, h*HD + e] = sum_t P[b,h,s,t] * V[t,e].
// Tile 128x256 (full hd in N -> P read exactly once), 512 threads = 8 waves
// (2M x 4N), wave tile 64x64 = 4x4 frags.
//
// Deep pipeline (T3/T4): 6 LDS buffers x 24 KB = 144 KB, prefetch depth 5
// (15 gload_lds/thread in flight = 120 KB/CU). Per K-step:
//   s_waitcnt vmcnt(12)   <- oldest tile's 3 loads done, 4 stages stay in flight
//   s_barrier             <- raw barrier: does NOT drain vmcnt
//   stage(t+5)            <- overwrites buf((t-1)%6); its readers finished
//                            before the barrier above (MFMA consumed ds_reads)
//   compute(t)            <- ds_read + 16 MFMA
// Never vmcnt(0) in the main loop; epilogue drains 12->9->6->3->0.
// Grid = 256 blocks (16 row-blocks x 16 (b,h)); XCD-clustered mapping keeps
// each (b,h)'s shared V panel (1 MB) hot in one XCD's L2.
// ---------------------------------------------------------------------------
__global__ __launch_bounds__(512) void mfma_pv(const bf16* __restrict__ Pm,
                                               const bf16* __restrict__ Vt,
                                               bf16* __restrict__ Cc) {
    // per buffer: A 128x32 (4096 shorts) | B 256x32 (8192 shorts) = 24 KB
    __shared__ __align__(16) short L[6][12288];

    const int tid = threadIdx.x;
    const int w = tid >> 6, lane = tid & 63;
    const int quad = lane >> 4, r = lane & 15;
    const int wr = (w >> 2) * 64, wc = (w & 3) * 64;  // wave's 64x64 subtile

    // XCD-clustered decomposition of 256 blocks: xcd = bid%8 (HW round-robin),
    // each XCD owns 2 (b,h) pairs x 16 row-blocks.
    const int bid = blockIdx.x;
    const int bh = (bid & 7) * 2 + ((bid >> 3) >> 4);  // 0..15, bijective
    const int rb = (bid >> 3) & 15;                    // row-block 0..15
    const int b = bh >> 2, h = bh & 3;

    const bf16* Ap = Pm + ((size_t)bh * S_ + (size_t)rb * 128) * S_;  // P[b,h] rows
    const bf16* Bp = Vt + (size_t)(h * B_ + b) * HD_ * S_;            // V^T panel

    const int srow = tid >> 2, scol = (tid & 3) << 3;  // 4 threads per 32-k row
    const int wbase = w * 512;                          // wave's 16-row LDS slab

    f32x4 acc[4][4] = {};

    auto stage = [&](int bs, int t) {
        short* sb = &L[bs][0];
        const int k0 = t * 32;
        GLOAD16(Ap + (size_t)srow * S_ + (k0 + scol), sb + wbase);               // P rows 0..127
        GLOAD16(Bp + (size_t)srow * S_ + (k0 + scol), sb + 4096 + wbase);        // V rows 0..127
        GLOAD16(Bp + (size_t)(128 + srow) * S_ + (k0 + scol), sb + 8192 + wbase);// V rows 128..255
    };
    auto compute = [&](int bs) {
        const s16x8* A8 = (const s16x8*)&L[bs][0];
        const s16x8* B8 = (const s16x8*)&L[bs][4096];
        s16x8 af[4], bfv[4];
#pragma unroll
        for (int i = 0; i < 4; i++) af[i] = A8[(wr + i * 16 + r) * 4 + quad];
#pragma unroll
        for (int j = 0; j < 4; j++) bfv[j] = B8[(wc + j * 16 + r) * 4 + quad];
#pragma unroll
        for (int i = 0; i < 4; i++)
#pragma unroll
            for (int j = 0; j < 4; j++)
                acc[i][j] = __builtin_amdgcn_mfma_f32_16x16x32_bf16(
                    af[i], bfv[j], acc[i][j], 0, 0, 0);
    };

#define PV_WAITB(N)                                           \
    asm volatile("s_waitcnt vmcnt(" #N ")" ::: "memory");     \
    __builtin_amdgcn_s_barrier();                             \
    __builtin_amdgcn_sched_barrier(0);

    stage(0, 0); stage(1, 1); stage(2, 2); stage(3, 3); stage(4, 4);

    int cb = 0, sn = 5;  // compute / stage buffer indices (mod 6)
#pragma unroll 1
    for (int t = 0; t < 59; ++t) {  // NT=64; stages t+5 = 5..63
        PV_WAITB(12);
        stage(sn, t + 5);
        compute(cb);
        cb = (cb == 5) ? 0 : cb + 1;
        sn = (sn == 5) ? 0 : sn + 1;
    }
    // epilogue: tiles 59..63, outstanding 15->12->9->6->3, no new stages
    PV_WAITB(12); compute(cb); cb = (cb == 5) ? 0 : cb + 1;
    PV_WAITB(9);  compute(cb); cb = (cb == 5) ? 0 : cb + 1;
    PV_WAITB(6);  compute(cb); cb = (cb == 5) ? 0 : cb + 1;
    PV_WAITB(3);  compute(cb); cb = (cb == 5) ? 0 : cb + 1;
    PV_WAITB(0);  compute(cb);
#undef PV_WAITB

    const int row0 = rb * 128 + wr + quad * 4;
    const int col0 = h * HD_ + wc + r;
    bf16* C = Cc + (size_t)b * S_ * D_;
#pragma unroll
    for (int i = 0; i < 4; i++)
#pragma unroll
        for (int j = 0; j < 4; j++)
#pragma unroll
            for (int p = 0; p < 4; p++)
                C[(size_t)(row0 + i * 16 + p) * D_ + col0 + j * 16] =
                    __float2bfloat16(acc[i][j][p]);
}

// fp32 -> bf16 (optionally scaled), 4 elems/thread
__global__ __launch_bounds__(256) void cvt_bf16(const float* __restrict__ in,
                                                bf16* __restrict__ out, int n,
                                                float scale) {
    const size_t i0 = ((size_t)blockIdx.x * 256 + threadIdx.x) * 4;
    if (i0 + 3 < (size_t)n) {
        const float4 v = *(const float4*)(in + i0);
        out[i0 + 0] = __float2bfloat16(v.x * scale);
        out[i0 + 1] = __float2bfloat16(v.y * scale);
        out[i0 + 2] = __float2bfloat16(v.z * scale);
        out[i0 + 3] = __float2bfloat16(v.w * scale);
    }
}

// Vraw [H, B*S, hd] -> Vt [H, B, hd, S]  (64x64 bf16 LDS tile transpose)
__global__ __launch_bounds__(256) void transpose_v(const bf16* __restrict__ in,
                                                   bf16* __restrict__ out) {
    const int h = blockIdx.z / B_, b = blockIdx.z % B_;
    const int e0 = blockIdx.x * 64, s0 = blockIdx.y * 64;
    __shared__ short t[64][66];
    const int tid = threadIdx.x;
    const int rr = tid >> 2;            // 0..63
    const int cc = (tid & 3) << 4;      // 0,16,32,48
    const bf16* ip = in + (((size_t)h * B_ * S_) + (size_t)b * S_ + s0) * HD_ + e0;
    const s16x8 v0 = *(const s16x8*)(ip + (size_t)rr * HD_ + cc);
    const s16x8 v1 = *(const s16x8*)(ip + (size_t)rr * HD_ + cc + 8);
#pragma unroll
    for (int i = 0; i < 8; i++) {
        t[rr][cc + i] = v0[i];
        t[rr][cc + 8 + i] = v1[i];
    }
    __syncthreads();
    bf16* op = out + (((size_t)h * B_ + b) * HD_ + e0 + rr) * S_ + s0 + cc;
    s16x8 o0, o1;
#pragma unroll
    for (int i = 0; i < 8; i++) {
        o0[i] = t[cc + i][rr];
        o1[i] = t[cc + 8 + i][rr];
    }
    *(s16x8*)op = o0;
    *(s16x8*)(op + 8) = o1;
}

// mag1[b,s] = ||emb[b,s,256:512]|| (fp64), v3[b,s] = emb[b,s,1023]
__global__ __launch_bounds__(256) void prep_kernel(const float* __restrict__ emb,
                                                   double* __restrict__ mag1d,
                                                   double* __restrict__ v3d) {
    const long row = blockIdx.x;
    const int tid = threadIdx.x;
    const float x = emb[row * D_ + 256 + tid];
    __shared__ double red[256];
    red[tid] = (double)x * (double)x;
    __syncthreads();
    for (int off = 128; off > 0; off >>= 1) {
        if (tid < off) red[tid] += red[tid + off];
        __syncthreads();
    }
    if (tid == 0) {
        mag1d[row] = sqrt(red[0]);
        v3d[row] = (double)emb[row * D_ + 1023];
    }
}

__global__ __launch_bounds__(256) void mean_kernel(const double* __restrict__ mag1d,
                                                   double* __restrict__ meand) {
    const int tid = threadIdx.x;
    __shared__ double red[256];
    double acc = 0.0;
    for (int b = 0; b < B_; b++) {
        double ss = 0.0;
        for (int i = tid; i < S_; i += 256) ss += mag1d[(long)b * S_ + i];
        __syncthreads();
        red[tid] = ss;
        __syncthreads();
        for (int off = 128; off > 0; off >>= 1) {
            if (tid < off) red[tid] += red[tid + off];
            __syncthreads();
        }
        if (tid == 0) {
            const double rb = red[0] / (double)S_;
            acc += rb * rb;
        }
        __syncthreads();
    }
    if (tid == 0) meand[0] = acc / (double)B_;
}

// Per row s (one b): softmax over all 4 heads (fp32, same op order as R2),
// write P bf16 (layout via p_h/p_row strides), accumulate avgw + rowsum.
__global__ __launch_bounds__(256) void softmax_fused(
    const float* __restrict__ scores, bf16* __restrict__ P, long p_h, int p_row,
    float* __restrict__ avgw, float* __restrict__ rowsum) {
    const int s = blockIdx.x, tid = threadIdx.x;
    __shared__ float red[256];
    float wacc[8] = {0, 0, 0, 0, 0, 0, 0, 0};
    for (int h = 0; h < H_; h++) {
        const float* rp = scores + ((size_t)h * S_ + s) * S_;
        bf16* pp = P + (size_t)h * p_h + (size_t)s * p_row;
        float v[8];
        float m = -1e30f;
#pragma unroll
        for (int i = 0; i < 8; i++) {
            v[i] = rp[tid + 256 * i];
            m = fmaxf(m, v[i]);
        }
        red[tid] = m;
        __syncthreads();
        for (int off = 128; off > 0; off >>= 1) {
            if (tid < off) red[tid] = fmaxf(red[tid], red[tid + off]);
            __syncthreads();
        }
        m = red[0];
        __syncthreads();
        float sum = 0.0f;
#pragma unroll
        for (int i = 0; i < 8; i++) {
            v[i] = expf(v[i] - m);
            sum += v[i];
        }
        red[tid] = sum;
        __syncthreads();
        for (int off = 128; off > 0; off >>= 1) {
            if (tid < off) red[tid] += red[tid + off];
            __syncthreads();
        }
        const float inv = 1.0f / red[0];
        __syncthreads();
#pragma unroll
        for (int i = 0; i < 8; i++) {
            const float wv = v[i] * inv;
            pp[tid + 256 * i] = __float2bfloat16(wv);
            wacc[i] += wv;
        }
    }
    float asum = 0.0f;
#pragma unroll
    for (int i = 0; i < 8; i++) {
        const float a = wacc[i] * 0.25f;
        avgw[(size_t)s * S_ + tid + 256 * i] = a;
        asum += a;
    }
    red[tid] = asum;
    __syncthreads();
    for (int off = 128; off > 0; off >>= 1) {
        if (tid < off) red[tid] += red[tid + off];
        __syncthreads();
    }
    if (tid == 0) rowsum[s] = red[0];
}

// y = proj + Wo_b + emb; LayerNorm(y) in place
__global__ __launch_bounds__(256) void ln_kernel(float* __restrict__ out,
                                                 const float* __restrict__ emb,
                                                 const float* __restrict__ wob,
                                                 const float* __restrict__ g,
                                                 const float* __restrict__ beta) {
    const long row = blockIdx.x;
    float* o = out + row * D_;
    const float* e = emb + row * D_;
    const int tid = threadIdx.x;
    __shared__ float red[256];
    float v[4];
    float sum = 0.0f;
#pragma unroll
    for (int i = 0; i < 4; i++) {
        const int c = tid + 256 * i;
        v[i] = o[c] + wob[c] + e[c];
        sum += v[i];
    }
    red[tid] = sum;
    __syncthreads();
    for (int off = 128; off > 0; off >>= 1) {
        if (tid < off) red[tid] += red[tid + off];
        __syncthreads();
    }
    const float mu = red[0] * (1.0f / 1024.0f);
    __syncthreads();
    float vs = 0.0f;
#pragma unroll
    for (int i = 0; i < 4; i++) {
        const float d = v[i] - mu;
        vs += d * d;
    }
    red[tid] = vs;
    __syncthreads();
    for (int off = 128; off > 0; off >>= 1) {
        if (tid < off) red[tid] += red[tid + off];
        __syncthreads();
    }
    const float var = red[0] * (1.0f / 1024.0f);
    const float inv = 1.0f / sqrtf(var + 1e-5f);
#pragma unroll
    for (int i = 0; i < 4; i++) {
        const int c = tid + 256 * i;
        o[c] = (v[i] - mu) * inv * g[c] + beta[c];
    }
}

__global__ __launch_bounds__(256) void guilt_kernel(const float* __restrict__ rowsum,
                                                    float* __restrict__ guilt) {
    const int b = blockIdx.x, tid = threadIdx.x;
    const float* r = rowsum + (long)b * S_;
    float* gq = guilt + (long)b * S_;
    __shared__ float red[256];
    float v[8];
    float m = -1e30f;
#pragma unroll
    for (int i = 0; i < 8; i++) {
        v[i] = r[tid + 256 * i];
        m = fmaxf(m, v[i]);
    }
    red[tid] = m;
    __syncthreads();
    for (int off = 128; off > 0; off >>= 1) {
        if (tid < off) red[tid] = fmaxf(red[tid], red[tid + off]);
        __syncthreads();
    }
    m = red[0];
    __syncthreads();
    float sum = 0.0f;
#pragma unroll
    for (int i = 0; i < 8; i++) {
        v[i] = expf(v[i] - m);
        sum += v[i];
    }
    red[tid] = sum;
    __syncthreads();
    for (int off = 128; off > 0; off >>= 1) {
        if (tid < off) red[tid] += red[tid + off];
        __syncthreads();
    }
    const float inv = 1.0f / red[0];
#pragma unroll
    for (int i = 0; i < 8; i++) gq[tid + 256 * i] = v[i] * inv;
}

extern "C" void kernel_launch(void* const* d_in, const int* in_sizes, int n_in,
                              void* d_out, int out_size, void* d_ws, size_t ws_size,
                              hipStream_t stream) {
    const float* emb = (const float*)d_in[0];
    const float* Wq = (const float*)d_in[1];
    const float* Wk = (const float*)d_in[2];
    const float* Wv = (const float*)d_in[3];
    const float* bias_sc = (const float*)d_in[4];
    const float* Wo_w = (const float*)d_in[5];
    const float* Wo_b = (const float*)d_in[6];
    const float* ln_g = (const float*)d_in[7];
    const float* ln_bt = (const float*)d_in[8];

    char* ws = (char*)d_ws;
    size_t off = 0;
    auto alloc = [&](size_t bytes) {
        size_t o = off;
        off = (off + bytes + 255) & ~(size_t)255;
        return o;
    };
    bf16* embb = (bf16*)(ws + alloc((size_t)B_ * S_ * D_ * 2));
    bf16* concat = embb;  // alias: embb dead after QKV GEMMs, concat written later
    bf16* Qm = (bf16*)(ws + alloc((size_t)H_ * B_ * S_ * HD_ * 2));  // [H,B*S,hd]
    bf16* Km = (bf16*)(ws + alloc((size_t)H_ * B_ * S_ * HD_ * 2));
    bf16* Vtb = (bf16*)(ws + alloc((size_t)H_ * B_ * HD_ * S_ * 2)); // [H,B,hd,S]
    bf16* Wqb = (bf16*)(ws + alloc((size_t)H_ * HD_ * HD_ * 2));
    bf16* Wkb = (bf16*)(ws + alloc((size_t)H_ * HD_ * HD_ * 2));
    bf16* Wvb = (bf16*)(ws + alloc((size_t)H_ * HD_ * HD_ * 2));
    bf16* Wob = (bf16*)(ws + alloc((size_t)D_ * D_ * 2));
    double* mag1d = (double*)(ws + alloc((size_t)B_ * S_ * 8));
    double* v3d = (double*)(ws + alloc((size_t)B_ * S_ * 8));
    double* meand = (double*)(ws + alloc(256));
    float* rowsum = (float*)(ws + alloc((size_t)B_ * S_ * 4));
    float* scores = (float*)(ws + alloc((size_t)H_ * S_ * S_ * 4));  // one b
    bf16* Vraw = (bf16*)scores;  // alias: Vraw consumed (transposed) before scores b=0
    bf16* P = (bf16*)(ws + off);  // Path A only: [B,H,S,S] bf16
    const size_t need_batched = off + (size_t)B_ * H_ * S_ * S_ * 2;
    const bool batched = ws_size >= need_batched;

    float* outp = (float*)d_out;
    float* avgw = outp + (size_t)B_ * S_ * D_;
    float* guilt = avgw + (size_t)B_ * S_ * S_;

    // casts (Q-scale 1/16 folded into Wq)
    cvt_bf16<<<(B_ * S_ * D_) / 1024, 256, 0, stream>>>(emb, embb, B_ * S_ * D_, 1.0f);
    cvt_bf16<<<(H_ * HD_ * HD_) / 1024, 256, 0, stream>>>(Wq, Wqb, H_ * HD_ * HD_, 0.0625f);
    cvt_bf16<<<(H_ * HD_ * HD_) / 1024, 256, 0, stream>>>(Wk, Wkb, H_ * HD_ * HD_, 1.0f);
    cvt_bf16<<<(H_ * HD_ * HD_) / 1024, 256, 0, stream>>>(Wv, Wvb, H_ * HD_ * HD_, 1.0f);
    cvt_bf16<<<(D_ * D_) / 1024, 256, 0, stream>>>(Wo_w, Wob, D_ * D_, 1.0f);

    prep_kernel<<<B_ * S_, 256, 0, stream>>>(emb, mag1d, v3d);
    mean_kernel<<<1, 256, 0, stream>>>(mag1d, meand);

    // QKV projections: MFMA, M = B*S (=8192), N = hd, K = hd, z = head
    {
        const dim3 g(HD_ / 128, (B_ * S_) / 128, H_);
        const long sQ = (long)B_ * S_ * HD_;
        mfma_nt<1><<<g, 256, 0, stream>>>(HD_, embb, D_, 0, HD_,
                                          Wqb, HD_, 0, (long)HD_ * HD_,
                                          Qm, HD_, 0, sQ, H_, 0,
                                          nullptr, nullptr, nullptr, nullptr);
        mfma_nt<1><<<g, 256, 0, stream>>>(HD_, embb, D_, 0, HD_,
                                          Wkb, HD_, 0, (long)HD_ * HD_,
                                          Km, HD_, 0, sQ, H_, 0,
                                          nullptr, nullptr, nullptr, nullptr);
        mfma_nt<1><<<g, 256, 0, stream>>>(HD_, embb, D_, 0, HD_,
                                          Wvb, HD_, 0, (long)HD_ * HD_,
                                          Vraw, HD_, 0, sQ, H_, 0,
                                          nullptr, nullptr, nullptr, nullptr);
    }
    transpose_v<<<dim3(HD_ / 64, S_ / 64, H_ * B_), 256, 0, stream>>>(Vraw, Vtb);

    for (int b = 0; b < B_; b++) {
        // scores[h,s,t] = Q.K^T + bias  (fp32 out, per-b buffer stays L3-warm)
        mfma_nt<3><<<dim3(S_ / 128, S_ / 128, H_), 256, 0, stream>>>(
            HD_,
            Qm + (size_t)b * S_ * HD_, HD_, 0, (long)B_ * S_ * HD_,
            Km + (size_t)b * S_ * HD_, HD_, 0, (long)B_ * S_ * HD_,
            scores, S_, 0, (long)S_ * S_,
            H_, b, mag1d, v3d, meand, bias_sc);
        if (batched) {
            softmax_fused<<<S_, 256, 0, stream>>>(
                scores, P + (size_t)b * H_ * S_ * S_, (long)S_ * S_, S_,
                avgw + (size_t)b * S_ * S_, rowsum + (size_t)b * S_);
        } else {
            // P bf16 in place over the fp32 scores rows (row stride 2S)
            softmax_fused<<<S_, 256, 0, stream>>>(
                scores, (bf16*)scores, 2L * S_ * S_, 2 * S_,
                avgw + (size_t)b * S_ * S_, rowsum + (size_t)b * S_);
            mfma_nt<1><<<dim3(HD_ / 128, S_ / 128, H_), 256, 0, stream>>>(
                S_,
                (const bf16*)scores, 2 * S_, 0, 2L * S_ * S_,
                Vtb + (size_t)b * HD_ * S_, S_, 0, (long)B_ * HD_ * S_,
                concat + (size_t)b * S_ * D_, D_, 0, HD_,
                H_, 0, nullptr, nullptr, nullptr, nullptr);
        }
    }
    if (batched) {
        // attended = P.V for all (b,h): deep-pipelined counted-vmcnt kernel,
        // P read exactly once, XCD-clustered V reuse.
        mfma_pv<<<256, 512, 0, stream>>>(P, Vtb, concat);
    }

    // out = concat @ Wo^T (MFMA, bf16 Wo)
    mfma_nt<0><<<dim3(D_ / 128, (B_ * S_) / 128, 1), 256, 0, stream>>>(
        D_, concat, D_, 0, 0, Wob, D_, 0, 0, outp, D_, 0, 0,
        1, 0, nullptr, nullptr, nullptr, nullptr);

    ln_kernel<<<B_ * S_, 256, 0, stream>>>(outp, emb, Wo_b, ln_g, ln_bt);
    guilt_kernel<<<B_, 256, 0, stream>>>(rowsum, guilt);
}